// Round 7
// baseline (1955.872 us; speedup 1.0000x reference)
//
#include <hip/hip_runtime.h>
#include <math.h>

#define T_LEN 65536
#define B_N   8
#define BT    (T_LEN * B_N)
#define L_N   16
#define RC    32
#define SC    64

#define C1    1024
#define HALO  1020
#define BUFSZ 2048
#define NT    512

// folded-weight per-layer arrays (14 x 32 = 448 floats)
#define A_AF0 0
#define A_AF1 32
#define A_AF2 64
#define A_CF0 96
#define A_CF1 128
#define A_BFC 160
#define A_AG0 192
#define A_AG1 224
#define A_AG2 256
#define A_CG0 288
#define A_CG1 320
#define A_BGC 352
#define A_BFF 384
#define A_BGF 416
#define FW_L  448
#define FW_BSUM (L_N * FW_L)      // 7168
#define FW_F32  (FW_BSUM + 64)    // 7232 floats
#define WSBF_N  (L_N * SC * RC)   // 32768 shorts
#define W1BF_N  (SC * SC)         // 4096 shorts

typedef float v2f __attribute__((ext_vector_type(2)));
typedef __attribute__((ext_vector_type(4))) float f4;
typedef __attribute__((ext_vector_type(4))) short bf4;
typedef __attribute__((ext_vector_type(8))) short bf8;

#define MFMA16(a, b, c) __builtin_amdgcn_mfma_f32_16x16x32_bf16(a, b, c, 0, 0, 0)

__device__ __forceinline__ v2f sp(float s) { return (v2f){s, s}; }
__device__ __forceinline__ float fast_rcp(float x) { return __builtin_amdgcn_rcpf(x); }

__device__ __forceinline__ float gated_fn(float fp, float gp) {
    float E = __expf(2.f * fp);
    float F = __expf(gp);
    return (E - 1.f) * F * fast_rcp((E + 1.f) * (F + 1.f));
}

__device__ __forceinline__ unsigned short f2bf(float f) {
    unsigned u = __float_as_uint(f);
    u += 0x7fffu + ((u >> 16) & 1u);
    return (unsigned short)(u >> 16);
}

// ---------------------------------------------------------------------------
// prep: fold gate weights (incl. mask-free biases BFF/BGF); Bsum; bf16 tables.
// ---------------------------------------------------------------------------
__global__ __launch_bounds__(256) void prep_kernel(
    const float* __restrict__ W_f, const float* __restrict__ W_g,
    const float* __restrict__ W_in, const float* __restrict__ b_in,
    const float* __restrict__ b_f, const float* __restrict__ b_g,
    const float* __restrict__ b_s, const float* __restrict__ W_s,
    const float* __restrict__ W_sk1, float* __restrict__ fw,
    short* __restrict__ fwh)
{
    int idx = blockIdx.x * 256 + threadIdx.x;
    if (idx < L_N * RC) {
        int i = idx >> 5, c = idx & 31;
        float af[3] = {0,0,0}, cf[3] = {0,0,0}, ag[3] = {0,0,0}, cg[3] = {0,0,0};
        for (int cin = 0; cin < RC; ++cin) {
            float wi = W_in[i * RC + cin];
            float bi = b_in[i * RC + cin];
            #pragma unroll
            for (int k = 0; k < 3; ++k) {
                float wf = W_f[((i * RC + c) * RC + cin) * 3 + k];
                float wg = W_g[((i * RC + c) * RC + cin) * 3 + k];
                af[k] = fmaf(wf, wi, af[k]);
                cf[k] = fmaf(wf, bi, cf[k]);
                ag[k] = fmaf(wg, wi, ag[k]);
                cg[k] = fmaf(wg, bi, cg[k]);
            }
        }
        float* p = fw + i * FW_L;
        float bfc = b_f[i * RC + c] + cf[2];
        float bgc = b_g[i * RC + c] + cg[2];
        p[A_AF0 + c] = af[0]; p[A_AF1 + c] = af[1]; p[A_AF2 + c] = af[2];
        p[A_CF0 + c] = cf[0]; p[A_CF1 + c] = cf[1];
        p[A_BFC + c] = bfc;
        p[A_AG0 + c] = ag[0]; p[A_AG1 + c] = ag[1]; p[A_AG2 + c] = ag[2];
        p[A_CG0 + c] = cg[0]; p[A_CG1 + c] = cg[1];
        p[A_BGC + c] = bgc;
        p[A_BFF + c] = bfc + cf[0] + cf[1];   // mask-free (t >= 2d) bias
        p[A_BGF + c] = bgc + cg[0] + cg[1];
    } else if (idx < L_N * RC + SC) {
        int s = idx - L_N * RC;
        float acc = 0.f;
        for (int i = 0; i < L_N; ++i) acc += b_s[i * SC + s];
        fw[FW_BSUM + s] = acc;
    } else if (idx < 576 + WSBF_N) {
        int j = idx - 576;
        fwh[j] = (short)f2bf(W_s[j]);            // [i][s][k] flat
    } else if (idx < 576 + WSBF_N + W1BF_N) {
        int j = idx - 576 - WSBF_N;
        fwh[WSBF_N + j] = (short)f2bf(W_sk1[j]); // [o][s] flat
    }
}

// ---------------------------------------------------------------------------
// fused kernel: residual chain (halo recompute) + per-layer bf16 skip-MFMA
// + head, one block per (b, 1024-t chunk).
// Register budget: acc[8][4] = 128 VGPR must stay resident. The allocator's
// occupancy heuristic targeted 4 waves/EU (128-VGPR cap) in R5/R6 and spilled
// 8 GB to scratch. amdgpu_waves_per_eu(2,2) (the max=2 is what launch_bounds
// cannot express) + LDS > 80 KB (1 block/CU by LDS too) pin the target at
// 2 waves/EU -> 256-VGPR budget.
// ---------------------------------------------------------------------------
__global__ __launch_bounds__(NT)
__attribute__((amdgpu_waves_per_eu(2, 2)))
void fused_kernel(
    const float* __restrict__ x, const float* __restrict__ fw,
    const short* __restrict__ Wsbf, const short* __restrict__ W1bf,
    const float* __restrict__ W_o, const float* __restrict__ b_o,
    const float* __restrict__ b_sk1, const float* __restrict__ W_sk2,
    const float* __restrict__ b_sk2, float* __restrict__ out)
{
    __shared__ __align__(16) float buf[2][BUFSZ];
    __shared__ __align__(16) char  Gb[1024 * 40];
    __shared__ __align__(16) float sGW[FW_L];
    __shared__ __align__(16) float sWo[32];
    __shared__ float sBo[1];
    __shared__ __align__(16) float sMisc[258]; // bsum[0..64) b1[64..128) w2[128..256) b2[256..258)
    __shared__ float pad_occ[5760];            // occupancy limiter: LDS > 80 KB

    int tid   = threadIdx.x;
    int b     = blockIdx.x >> 6;
    int chunk = blockIdx.x & 63;
    int t0    = chunk * C1;
    bool safe = (chunk >= 2);           // all t >= 2*d_max in computed range

    int wv   = tid >> 6;
    int lane = tid & 63;
    int m    = lane & 15;
    int q    = lane >> 4;

    if (tid < 64) { sMisc[tid] = fw[FW_BSUM + tid]; sMisc[64 + tid] = b_sk1[tid]; }
    if (tid < 128) sMisc[128 + tid] = W_sk2[tid];
    if (tid < 2)   sMisc[256 + tid] = b_sk2[tid];

    const float* xb = x + (size_t)b * T_LEN;
    // keep pad_occ alive: data-dependent, practically-never-true touch
    if (__float_as_uint(xb[0]) == 0xDEADBEEFu) pad_occ[tid] = 1.f;

    for (int p = tid; p < C1 + HALO; p += NT) {
        int t = t0 - HALO + p;
        buf[0][p] = (t >= 0) ? xb[t] : 0.f;
    }

    f4 acc[8][4];
    #pragma unroll
    for (int tt = 0; tt < 8; ++tt)
        #pragma unroll
        for (int st = 0; st < 4; ++st) acc[tt][st] = (f4){0.f, 0.f, 0.f, 0.f};

    int cur = 0;
    int rem = HALO;
    for (int i = 0; i < L_N; ++i) {
        int d    = 1 << (i & 7);
        int remN = rem - 2 * d;
        int lo   = HALO - remN;
        int nxt  = cur ^ 1;

        if (tid < FW_L) sGW[tid] = fw[i * FW_L + tid];
        if (tid >= FW_L && tid < FW_L + 32) sWo[tid - FW_L] = W_o[i * 32 + (tid - FW_L)];
        if (tid == FW_L + 32) sBo[0] = b_o[i];

        bf8 bfrag[4];
        #pragma unroll
        for (int st = 0; st < 4; ++st)
            bfrag[st] = *(const bf8*)(Wsbf + i * (SC * RC) + (st * 16 + m) * RC + q * 8);

        __syncthreads();   // weights staged; prev G consumed; buf[cur] ready

        // ---- per-thread taps/masks ----
        int  pj[4], row[4];
        bool inr[4], pok[4], on[4];
        float s2v[4], s1v[4], s0v[4];
        v2f m0p[2], m1p[2];
        #pragma unroll
        for (int j = 0; j < 4; ++j) {
            int p = lo + tid + j * NT;
            int t = t0 - HALO + p;
            pj[j]  = p;
            row[j] = p - HALO;
            inr[j] = (p < C1 + HALO);
            pok[j] = inr[j] && (p >= HALO);
            on[j]  = inr[j] && (t >= 0);
            if (inr[j]) {
                s2v[j] = buf[cur][p];
                s1v[j] = buf[cur][p - d];
                s0v[j] = buf[cur][p - 2 * d];
            } else { s2v[j] = s1v[j] = s0v[j] = 0.f; }
            if (!safe) {
                float mm1 = (t - d     >= 0) ? 1.f : 0.f;
                float mm0 = (t - 2 * d >= 0) ? 1.f : 0.f;
                if (j & 1) { m1p[j >> 1].y = mm1; m0p[j >> 1].y = mm0; }
                else       { m1p[j >> 1].x = mm1; m0p[j >> 1].x = mm0; }
            }
        }
        v2f s0p[2] = {{s0v[0], s0v[1]}, {s0v[2], s0v[3]}};
        v2f s1p[2] = {{s1v[0], s1v[1]}, {s1v[2], s1v[3]}};
        v2f s2p[2] = {{s2v[0], s2v[1]}, {s2v[2], s2v[3]}};
        v2f accp[2] = {{0.f, 0.f}, {0.f, 0.f}};

        // ---- two 16-channel halves: gate -> G(bf16) -> MFMA ----
        #pragma unroll
        for (int h = 0; h < 2; ++h) {
            #pragma unroll
            for (int c4g = 0; c4g < 4; ++c4g) {
                int c0 = h * 16 + c4g * 4;
                f4 vaf0 = *(const f4*)(sGW + A_AF0 + c0);
                f4 vaf1 = *(const f4*)(sGW + A_AF1 + c0);
                f4 vaf2 = *(const f4*)(sGW + A_AF2 + c0);
                f4 vag0 = *(const f4*)(sGW + A_AG0 + c0);
                f4 vag1 = *(const f4*)(sGW + A_AG1 + c0);
                f4 vag2 = *(const f4*)(sGW + A_AG2 + c0);
                f4 vwo  = *(const f4*)(sWo + c0 - h * 16 + (h ? 16 : 0));
                f4 vbf  = *(const f4*)(sGW + (safe ? A_BFF : A_BFC) + c0);
                f4 vbg  = *(const f4*)(sGW + (safe ? A_BGF : A_BGC) + c0);
                f4 vcf0, vcf1, vcg0, vcg1;
                if (!safe) {
                    vcf0 = *(const f4*)(sGW + A_CF0 + c0);
                    vcf1 = *(const f4*)(sGW + A_CF1 + c0);
                    vcg0 = *(const f4*)(sGW + A_CG0 + c0);
                    vcg1 = *(const f4*)(sGW + A_CG1 + c0);
                }
                v2f gg[4][2];
                #pragma unroll
                for (int e = 0; e < 4; ++e) {
                    #pragma unroll
                    for (int jp = 0; jp < 2; ++jp) {
                        v2f fp = sp(vbf[e]);
                        v2f gp = sp(vbg[e]);
                        if (!safe) {
                            fp = fp + m0p[jp] * sp(vcf0[e]) + m1p[jp] * sp(vcf1[e]);
                            gp = gp + m0p[jp] * sp(vcg0[e]) + m1p[jp] * sp(vcg1[e]);
                        }
                        fp = fp + s0p[jp] * sp(vaf0[e]) + s1p[jp] * sp(vaf1[e]) + s2p[jp] * sp(vaf2[e]);
                        gp = gp + s0p[jp] * sp(vag0[e]) + s1p[jp] * sp(vag1[e]) + s2p[jp] * sp(vag2[e]);
                        v2f g;
                        g.x = gated_fn(fp.x, gp.x);
                        g.y = gated_fn(fp.y, gp.y);
                        gg[e][jp] = g;
                        accp[jp] = accp[jp] + g * sp(vwo[e]);
                    }
                }
                #pragma unroll
                for (int j = 0; j < 4; ++j) {
                    if (pok[j]) {
                        int jp = j >> 1;
                        bf4 v;
                        v[0] = (short)f2bf((j & 1) ? gg[0][jp].y : gg[0][jp].x);
                        v[1] = (short)f2bf((j & 1) ? gg[1][jp].y : gg[1][jp].x);
                        v[2] = (short)f2bf((j & 1) ? gg[2][jp].y : gg[2][jp].x);
                        v[3] = (short)f2bf((j & 1) ? gg[3][jp].y : gg[3][jp].x);
                        *(bf4*)(Gb + row[j] * 40 + c4g * 8) = v;
                    }
                }
            }

            // residual writeback (after both halves' acc, before the last sync)
            if (h == 1 && i < 15) {
                #pragma unroll
                for (int j = 0; j < 4; ++j) {
                    if (inr[j]) {
                        float a = (j & 1) ? accp[j >> 1].y : accp[j >> 1].x;
                        float outv = s2v[j] + sBo[0] + a;
                        if (!safe && !on[j]) outv = 0.f;
                        buf[nxt][pj[j]] = outv;
                    }
                }
            }
            __syncthreads();   // G half ready

            // MFMA: A-frag carries this half's 16 channels, zeros elsewhere
            #pragma unroll
            for (int tt = 0; tt < 8; ++tt) {
                int gr = (wv * 8 + tt) * 16 + m;
                bf8 av = {0, 0, 0, 0, 0, 0, 0, 0};
                if ((q >> 1) == h) {
                    const char* ap = Gb + gr * 40 + (q & 1) * 16;
                    bf4 a0 = *(const bf4*)ap;
                    bf4 a1 = *(const bf4*)(ap + 8);
                    av = __builtin_shufflevector(a0, a1, 0, 1, 2, 3, 4, 5, 6, 7);
                }
                #pragma unroll
                for (int st = 0; st < 4; ++st)
                    acc[tt][st] = MFMA16(av, bfrag[st], acc[tt][st]);
            }
            if (h == 0) __syncthreads();   // G consumed before half-2 stores
        }
        cur = nxt;
        rem = remN;
    }

    // ---- head: per-wave, per-t-tile: bf16 LDS round-trip + MFMA(K=64) ----
    __syncthreads();   // layer-15 MFMA done; G region reused as scratch
    bf8 w1f[4][2];
    #pragma unroll
    for (int ot = 0; ot < 4; ++ot)
        #pragma unroll
        for (int kc = 0; kc < 2; ++kc)
            w1f[ot][kc] = *(const bf8*)(W1bf + (ot * 16 + m) * SC + kc * 32 + q * 8);

    char* hs = Gb + wv * 2304;   // 16 rows x 144 B per wave
    float b20 = sMisc[256], b21 = sMisc[257];
    #pragma unroll
    for (int tt = 0; tt < 8; ++tt) {
        #pragma unroll
        for (int st = 0; st < 4; ++st) {
            int s = st * 16 + m;
            float bs = sMisc[s];
            #pragma unroll
            for (int r = 0; r < 4; ++r)
                *(unsigned short*)(hs + (q * 4 + r) * 144 + s * 2) = f2bf(acc[tt][st][r] + bs);
        }
        f4 hacc[4];
        #pragma unroll
        for (int ot = 0; ot < 4; ++ot) hacc[ot] = (f4){0.f, 0.f, 0.f, 0.f};
        #pragma unroll
        for (int kc = 0; kc < 2; ++kc) {
            bf8 af = *(const bf8*)(hs + m * 144 + kc * 64 + q * 16);
            #pragma unroll
            for (int ot = 0; ot < 4; ++ot)
                hacc[ot] = MFMA16(af, w1f[ot][kc], hacc[ot]);
        }
        float p0[4] = {0.f, 0.f, 0.f, 0.f}, p1[4] = {0.f, 0.f, 0.f, 0.f};
        #pragma unroll
        for (int ot = 0; ot < 4; ++ot) {
            int o = ot * 16 + m;
            float w20 = sMisc[128 + o], w21 = sMisc[192 + o], b1v = sMisc[64 + o];
            #pragma unroll
            for (int r = 0; r < 4; ++r) {
                float hv = fmaxf(hacc[ot][r] + b1v, 0.f);
                p0[r] = fmaf(w20, hv, p0[r]);
                p1[r] = fmaf(w21, hv, p1[r]);
            }
        }
        #pragma unroll
        for (int msk = 1; msk <= 8; msk <<= 1)
            #pragma unroll
            for (int r = 0; r < 4; ++r) {
                p0[r] += __shfl_xor(p0[r], msk);
                p1[r] += __shfl_xor(p1[r], msk);
            }
        if (m == 0) {
            int t = t0 + (wv * 8 + tt) * 16 + q * 4;
            size_t gi = (size_t)b * T_LEN + t;
            f4 mv, sv;
            #pragma unroll
            for (int r = 0; r < 4; ++r) {
                mv[r] = p0[r] + b20;
                sv[r] = __expf(0.5f * (p1[r] + b21));
            }
            *(f4*)(out + gi)      = mv;
            *(f4*)(out + BT + gi) = sv;
        }
    }
}

// ---------------------------------------------------------------------------
extern "C" void kernel_launch(void* const* d_in, const int* in_sizes, int n_in,
                              void* d_out, int out_size, void* d_ws, size_t ws_size,
                              hipStream_t stream) {
    const float* x     = (const float*)d_in[0];
    const float* W_in  = (const float*)d_in[1];
    const float* b_in  = (const float*)d_in[2];
    const float* W_f   = (const float*)d_in[3];
    const float* b_f   = (const float*)d_in[4];
    const float* W_g   = (const float*)d_in[5];
    const float* b_g   = (const float*)d_in[6];
    const float* W_s   = (const float*)d_in[7];
    const float* b_s   = (const float*)d_in[8];
    const float* W_o   = (const float*)d_in[9];
    const float* b_o   = (const float*)d_in[10];
    const float* W_sk1 = (const float*)d_in[11];
    const float* b_sk1 = (const float*)d_in[12];
    const float* W_sk2 = (const float*)d_in[13];
    const float* b_sk2 = (const float*)d_in[14];
    float* outp = (float*)d_out;

    float* fw  = (float*)d_ws;              // FW_F32 floats
    short* fwh = (short*)(fw + FW_F32);     // bf16 tables (Wsbf, W1bf)

    int prep_items = 576 + WSBF_N + W1BF_N;
    prep_kernel<<<(prep_items + 255) / 256, 256, 0, stream>>>(
        W_f, W_g, W_in, b_in, b_f, b_g, b_s, W_s, W_sk1, fw, fwh);
    fused_kernel<<<B_N * (T_LEN / C1), NT, 0, stream>>>(
        x, fw, fwh, fwh + WSBF_N, W_o, b_o, b_sk1, W_sk2, b_sk2, outp);
}

// Round 8
// 1950.670 us; speedup vs baseline: 1.0027x; 1.0027x over previous
//
#include <hip/hip_runtime.h>
#include <math.h>

#define T_LEN 65536
#define B_N   8
#define BT    (T_LEN * B_N)
#define L_N   16
#define RC    32
#define SC    64

#define C1    1024
#define HALO  1020
// BUFSZ enlarged beyond the needed 2044: LDS ballast. Total static LDS
// ~82.4 KB > 81920 B forces 1 block/CU (gfx950 LDS = 160 KB/CU), i.e.
// 2 waves/EU, which raises the register allocator's per-wave VGPR budget
// to 256+ so the 128-VGPR skip accumulator stays resident (R5-R7 spilled
// 8 GB/dispatch to scratch at the 4-waves/EU 128-reg budget).
#define BUFSZ 4800
#define NT    512

// folded-weight per-layer arrays (14 x 32 = 448 floats)
#define A_AF0 0
#define A_AF1 32
#define A_AF2 64
#define A_CF0 96
#define A_CF1 128
#define A_BFC 160
#define A_AG0 192
#define A_AG1 224
#define A_AG2 256
#define A_CG0 288
#define A_CG1 320
#define A_BGC 352
#define A_BFF 384
#define A_BGF 416
#define FW_L  448
#define FW_BSUM (L_N * FW_L)      // 7168
#define FW_F32  (FW_BSUM + 64)    // 7232 floats
#define WSBF_N  (L_N * SC * RC)   // 32768 shorts
#define W1BF_N  (SC * SC)         // 4096 shorts

typedef float v2f __attribute__((ext_vector_type(2)));
typedef __attribute__((ext_vector_type(4))) float f4;
typedef __attribute__((ext_vector_type(4))) short bf4;
typedef __attribute__((ext_vector_type(8))) short bf8;

#define MFMA16(a, b, c) __builtin_amdgcn_mfma_f32_16x16x32_bf16(a, b, c, 0, 0, 0)

__device__ __forceinline__ v2f sp(float s) { return (v2f){s, s}; }
__device__ __forceinline__ float fast_rcp(float x) { return __builtin_amdgcn_rcpf(x); }

__device__ __forceinline__ float gated_fn(float fp, float gp) {
    float E = __expf(2.f * fp);
    float F = __expf(gp);
    return (E - 1.f) * F * fast_rcp((E + 1.f) * (F + 1.f));
}

__device__ __forceinline__ unsigned short f2bf(float f) {
    unsigned u = __float_as_uint(f);
    u += 0x7fffu + ((u >> 16) & 1u);
    return (unsigned short)(u >> 16);
}

// ---------------------------------------------------------------------------
// prep: fold gate weights (incl. mask-free biases BFF/BGF); Bsum; bf16 tables.
// ---------------------------------------------------------------------------
__global__ __launch_bounds__(256) void prep_kernel(
    const float* __restrict__ W_f, const float* __restrict__ W_g,
    const float* __restrict__ W_in, const float* __restrict__ b_in,
    const float* __restrict__ b_f, const float* __restrict__ b_g,
    const float* __restrict__ b_s, const float* __restrict__ W_s,
    const float* __restrict__ W_sk1, float* __restrict__ fw,
    short* __restrict__ fwh)
{
    int idx = blockIdx.x * 256 + threadIdx.x;
    if (idx < L_N * RC) {
        int i = idx >> 5, c = idx & 31;
        float af[3] = {0,0,0}, cf[3] = {0,0,0}, ag[3] = {0,0,0}, cg[3] = {0,0,0};
        for (int cin = 0; cin < RC; ++cin) {
            float wi = W_in[i * RC + cin];
            float bi = b_in[i * RC + cin];
            #pragma unroll
            for (int k = 0; k < 3; ++k) {
                float wf = W_f[((i * RC + c) * RC + cin) * 3 + k];
                float wg = W_g[((i * RC + c) * RC + cin) * 3 + k];
                af[k] = fmaf(wf, wi, af[k]);
                cf[k] = fmaf(wf, bi, cf[k]);
                ag[k] = fmaf(wg, wi, ag[k]);
                cg[k] = fmaf(wg, bi, cg[k]);
            }
        }
        float* p = fw + i * FW_L;
        float bfc = b_f[i * RC + c] + cf[2];
        float bgc = b_g[i * RC + c] + cg[2];
        p[A_AF0 + c] = af[0]; p[A_AF1 + c] = af[1]; p[A_AF2 + c] = af[2];
        p[A_CF0 + c] = cf[0]; p[A_CF1 + c] = cf[1];
        p[A_BFC + c] = bfc;
        p[A_AG0 + c] = ag[0]; p[A_AG1 + c] = ag[1]; p[A_AG2 + c] = ag[2];
        p[A_CG0 + c] = cg[0]; p[A_CG1 + c] = cg[1];
        p[A_BGC + c] = bgc;
        p[A_BFF + c] = bfc + cf[0] + cf[1];   // mask-free (t >= 2d) bias
        p[A_BGF + c] = bgc + cg[0] + cg[1];
    } else if (idx < L_N * RC + SC) {
        int s = idx - L_N * RC;
        float acc = 0.f;
        for (int i = 0; i < L_N; ++i) acc += b_s[i * SC + s];
        fw[FW_BSUM + s] = acc;
    } else if (idx < 576 + WSBF_N) {
        int j = idx - 576;
        fwh[j] = (short)f2bf(W_s[j]);            // [i][s][k] flat
    } else if (idx < 576 + WSBF_N + W1BF_N) {
        int j = idx - 576 - WSBF_N;
        fwh[WSBF_N + j] = (short)f2bf(W_sk1[j]); // [o][s] flat
    }
}

// ---------------------------------------------------------------------------
// fused kernel: residual chain (halo recompute) + per-layer bf16 skip-MFMA
// + head, one block per (b, 1024-t chunk). See BUFSZ note for the LDS-ballast
// occupancy pin (1 block/CU -> 2 waves/EU -> 256-VGPR budget, no acc spill).
// ---------------------------------------------------------------------------
__global__ __launch_bounds__(NT)
__attribute__((amdgpu_waves_per_eu(2, 2)))
void fused_kernel(
    const float* __restrict__ x, const float* __restrict__ fw,
    const short* __restrict__ Wsbf, const short* __restrict__ W1bf,
    const float* __restrict__ W_o, const float* __restrict__ b_o,
    const float* __restrict__ b_sk1, const float* __restrict__ W_sk2,
    const float* __restrict__ b_sk2, float* __restrict__ out)
{
    __shared__ __align__(16) float buf[2][BUFSZ];   // ballast-sized, see BUFSZ
    __shared__ __align__(16) char  Gb[1024 * 40];
    __shared__ __align__(16) float sGW[FW_L];
    __shared__ __align__(16) float sWo[32];
    __shared__ float sBo[1];
    __shared__ __align__(16) float sMisc[258]; // bsum[0..64) b1[64..128) w2[128..256) b2[256..258)

    int tid   = threadIdx.x;
    int b     = blockIdx.x >> 6;
    int chunk = blockIdx.x & 63;
    int t0    = chunk * C1;
    bool safe = (chunk >= 2);           // all t >= 2*d_max in computed range

    int wv   = tid >> 6;
    int lane = tid & 63;
    int m    = lane & 15;
    int q    = lane >> 4;

    if (tid < 64) { sMisc[tid] = fw[FW_BSUM + tid]; sMisc[64 + tid] = b_sk1[tid]; }
    if (tid < 128) sMisc[128 + tid] = W_sk2[tid];
    if (tid < 2)   sMisc[256 + tid] = b_sk2[tid];

    const float* xb = x + (size_t)b * T_LEN;
    for (int p = tid; p < C1 + HALO; p += NT) {
        int t = t0 - HALO + p;
        buf[0][p] = (t >= 0) ? xb[t] : 0.f;
    }

    f4 acc[8][4];
    #pragma unroll
    for (int tt = 0; tt < 8; ++tt)
        #pragma unroll
        for (int st = 0; st < 4; ++st) acc[tt][st] = (f4){0.f, 0.f, 0.f, 0.f};

    int cur = 0;
    int rem = HALO;
    for (int i = 0; i < L_N; ++i) {
        int d    = 1 << (i & 7);
        int remN = rem - 2 * d;
        int lo   = HALO - remN;
        int nxt  = cur ^ 1;

        if (tid < FW_L) sGW[tid] = fw[i * FW_L + tid];
        if (tid >= FW_L && tid < FW_L + 32) sWo[tid - FW_L] = W_o[i * 32 + (tid - FW_L)];
        if (tid == FW_L + 32) sBo[0] = b_o[i];

        bf8 bfrag[4];
        #pragma unroll
        for (int st = 0; st < 4; ++st)
            bfrag[st] = *(const bf8*)(Wsbf + i * (SC * RC) + (st * 16 + m) * RC + q * 8);

        __syncthreads();   // weights staged; prev G consumed; buf[cur] ready

        // ---- per-thread taps/masks ----
        int  pj[4], row[4];
        bool inr[4], pok[4], on[4];
        float s2v[4], s1v[4], s0v[4];
        v2f m0p[2], m1p[2];
        #pragma unroll
        for (int j = 0; j < 4; ++j) {
            int p = lo + tid + j * NT;
            int t = t0 - HALO + p;
            pj[j]  = p;
            row[j] = p - HALO;
            inr[j] = (p < C1 + HALO);
            pok[j] = inr[j] && (p >= HALO);
            on[j]  = inr[j] && (t >= 0);
            if (inr[j]) {
                s2v[j] = buf[cur][p];
                s1v[j] = buf[cur][p - d];
                s0v[j] = buf[cur][p - 2 * d];
            } else { s2v[j] = s1v[j] = s0v[j] = 0.f; }
            if (!safe) {
                float mm1 = (t - d     >= 0) ? 1.f : 0.f;
                float mm0 = (t - 2 * d >= 0) ? 1.f : 0.f;
                if (j & 1) { m1p[j >> 1].y = mm1; m0p[j >> 1].y = mm0; }
                else       { m1p[j >> 1].x = mm1; m0p[j >> 1].x = mm0; }
            }
        }
        v2f s0p[2] = {{s0v[0], s0v[1]}, {s0v[2], s0v[3]}};
        v2f s1p[2] = {{s1v[0], s1v[1]}, {s1v[2], s1v[3]}};
        v2f s2p[2] = {{s2v[0], s2v[1]}, {s2v[2], s2v[3]}};
        v2f accp[2] = {{0.f, 0.f}, {0.f, 0.f}};

        // ---- two 16-channel halves: gate -> G(bf16) -> MFMA ----
        #pragma unroll
        for (int h = 0; h < 2; ++h) {
            #pragma unroll
            for (int c4g = 0; c4g < 4; ++c4g) {
                int c0 = h * 16 + c4g * 4;
                f4 vaf0 = *(const f4*)(sGW + A_AF0 + c0);
                f4 vaf1 = *(const f4*)(sGW + A_AF1 + c0);
                f4 vaf2 = *(const f4*)(sGW + A_AF2 + c0);
                f4 vag0 = *(const f4*)(sGW + A_AG0 + c0);
                f4 vag1 = *(const f4*)(sGW + A_AG1 + c0);
                f4 vag2 = *(const f4*)(sGW + A_AG2 + c0);
                f4 vwo  = *(const f4*)(sWo + c0 - h * 16 + (h ? 16 : 0));
                f4 vbf  = *(const f4*)(sGW + (safe ? A_BFF : A_BFC) + c0);
                f4 vbg  = *(const f4*)(sGW + (safe ? A_BGF : A_BGC) + c0);
                f4 vcf0, vcf1, vcg0, vcg1;
                if (!safe) {
                    vcf0 = *(const f4*)(sGW + A_CF0 + c0);
                    vcf1 = *(const f4*)(sGW + A_CF1 + c0);
                    vcg0 = *(const f4*)(sGW + A_CG0 + c0);
                    vcg1 = *(const f4*)(sGW + A_CG1 + c0);
                }
                v2f gg[4][2];
                #pragma unroll
                for (int e = 0; e < 4; ++e) {
                    #pragma unroll
                    for (int jp = 0; jp < 2; ++jp) {
                        v2f fp = sp(vbf[e]);
                        v2f gp = sp(vbg[e]);
                        if (!safe) {
                            fp = fp + m0p[jp] * sp(vcf0[e]) + m1p[jp] * sp(vcf1[e]);
                            gp = gp + m0p[jp] * sp(vcg0[e]) + m1p[jp] * sp(vcg1[e]);
                        }
                        fp = fp + s0p[jp] * sp(vaf0[e]) + s1p[jp] * sp(vaf1[e]) + s2p[jp] * sp(vaf2[e]);
                        gp = gp + s0p[jp] * sp(vag0[e]) + s1p[jp] * sp(vag1[e]) + s2p[jp] * sp(vag2[e]);
                        v2f g;
                        g.x = gated_fn(fp.x, gp.x);
                        g.y = gated_fn(fp.y, gp.y);
                        gg[e][jp] = g;
                        accp[jp] = accp[jp] + g * sp(vwo[e]);
                    }
                }
                #pragma unroll
                for (int j = 0; j < 4; ++j) {
                    if (pok[j]) {
                        int jp = j >> 1;
                        bf4 v;
                        v[0] = (short)f2bf((j & 1) ? gg[0][jp].y : gg[0][jp].x);
                        v[1] = (short)f2bf((j & 1) ? gg[1][jp].y : gg[1][jp].x);
                        v[2] = (short)f2bf((j & 1) ? gg[2][jp].y : gg[2][jp].x);
                        v[3] = (short)f2bf((j & 1) ? gg[3][jp].y : gg[3][jp].x);
                        *(bf4*)(Gb + row[j] * 40 + c4g * 8) = v;
                    }
                }
            }

            // residual writeback (after both halves' acc, before the last sync)
            if (h == 1 && i < 15) {
                #pragma unroll
                for (int j = 0; j < 4; ++j) {
                    if (inr[j]) {
                        float a = (j & 1) ? accp[j >> 1].y : accp[j >> 1].x;
                        float outv = s2v[j] + sBo[0] + a;
                        if (!safe && !on[j]) outv = 0.f;
                        buf[nxt][pj[j]] = outv;
                    }
                }
            }
            __syncthreads();   // G half ready

            // MFMA: A-frag carries this half's 16 channels, zeros elsewhere
            #pragma unroll
            for (int tt = 0; tt < 8; ++tt) {
                int gr = (wv * 8 + tt) * 16 + m;
                bf8 av = {0, 0, 0, 0, 0, 0, 0, 0};
                if ((q >> 1) == h) {
                    const char* ap = Gb + gr * 40 + (q & 1) * 16;
                    bf4 a0 = *(const bf4*)ap;
                    bf4 a1 = *(const bf4*)(ap + 8);
                    av = __builtin_shufflevector(a0, a1, 0, 1, 2, 3, 4, 5, 6, 7);
                }
                #pragma unroll
                for (int st = 0; st < 4; ++st)
                    acc[tt][st] = MFMA16(av, bfrag[st], acc[tt][st]);
            }
            if (h == 0) __syncthreads();   // G consumed before half-2 stores
        }
        cur = nxt;
        rem = remN;
    }

    // ---- head: per-wave, per-t-tile: bf16 LDS round-trip + MFMA(K=64) ----
    __syncthreads();   // layer-15 MFMA done; G region reused as scratch
    bf8 w1f[4][2];
    #pragma unroll
    for (int ot = 0; ot < 4; ++ot)
        #pragma unroll
        for (int kc = 0; kc < 2; ++kc)
            w1f[ot][kc] = *(const bf8*)(W1bf + (ot * 16 + m) * SC + kc * 32 + q * 8);

    char* hs = Gb + wv * 2304;   // 16 rows x 144 B per wave
    float b20 = sMisc[256], b21 = sMisc[257];
    #pragma unroll
    for (int tt = 0; tt < 8; ++tt) {
        #pragma unroll
        for (int st = 0; st < 4; ++st) {
            int s = st * 16 + m;
            float bs = sMisc[s];
            #pragma unroll
            for (int r = 0; r < 4; ++r)
                *(unsigned short*)(hs + (q * 4 + r) * 144 + s * 2) = f2bf(acc[tt][st][r] + bs);
        }
        f4 hacc[4];
        #pragma unroll
        for (int ot = 0; ot < 4; ++ot) hacc[ot] = (f4){0.f, 0.f, 0.f, 0.f};
        #pragma unroll
        for (int kc = 0; kc < 2; ++kc) {
            bf8 af = *(const bf8*)(hs + m * 144 + kc * 64 + q * 16);
            #pragma unroll
            for (int ot = 0; ot < 4; ++ot)
                hacc[ot] = MFMA16(af, w1f[ot][kc], hacc[ot]);
        }
        float p0[4] = {0.f, 0.f, 0.f, 0.f}, p1[4] = {0.f, 0.f, 0.f, 0.f};
        #pragma unroll
        for (int ot = 0; ot < 4; ++ot) {
            int o = ot * 16 + m;
            float w20 = sMisc[128 + o], w21 = sMisc[192 + o], b1v = sMisc[64 + o];
            #pragma unroll
            for (int r = 0; r < 4; ++r) {
                float hv = fmaxf(hacc[ot][r] + b1v, 0.f);
                p0[r] = fmaf(w20, hv, p0[r]);
                p1[r] = fmaf(w21, hv, p1[r]);
            }
        }
        #pragma unroll
        for (int msk = 1; msk <= 8; msk <<= 1)
            #pragma unroll
            for (int r = 0; r < 4; ++r) {
                p0[r] += __shfl_xor(p0[r], msk);
                p1[r] += __shfl_xor(p1[r], msk);
            }
        if (m == 0) {
            int t = t0 + (wv * 8 + tt) * 16 + q * 4;
            size_t gi = (size_t)b * T_LEN + t;
            f4 mv, sv;
            #pragma unroll
            for (int r = 0; r < 4; ++r) {
                mv[r] = p0[r] + b20;
                sv[r] = __expf(0.5f * (p1[r] + b21));
            }
            *(f4*)(out + gi)      = mv;
            *(f4*)(out + BT + gi) = sv;
        }
    }
}

// ---------------------------------------------------------------------------
extern "C" void kernel_launch(void* const* d_in, const int* in_sizes, int n_in,
                              void* d_out, int out_size, void* d_ws, size_t ws_size,
                              hipStream_t stream) {
    const float* x     = (const float*)d_in[0];
    const float* W_in  = (const float*)d_in[1];
    const float* b_in  = (const float*)d_in[2];
    const float* W_f   = (const float*)d_in[3];
    const float* b_f   = (const float*)d_in[4];
    const float* W_g   = (const float*)d_in[5];
    const float* b_g   = (const float*)d_in[6];
    const float* W_s   = (const float*)d_in[7];
    const float* b_s   = (const float*)d_in[8];
    const float* W_o   = (const float*)d_in[9];
    const float* b_o   = (const float*)d_in[10];
    const float* W_sk1 = (const float*)d_in[11];
    const float* b_sk1 = (const float*)d_in[12];
    const float* W_sk2 = (const float*)d_in[13];
    const float* b_sk2 = (const float*)d_in[14];
    float* outp = (float*)d_out;

    float* fw  = (float*)d_ws;              // FW_F32 floats
    short* fwh = (short*)(fw + FW_F32);     // bf16 tables (Wsbf, W1bf)

    int prep_items = 576 + WSBF_N + W1BF_N;
    prep_kernel<<<(prep_items + 255) / 256, 256, 0, stream>>>(
        W_f, W_g, W_in, b_in, b_f, b_g, b_s, W_s, W_sk1, fw, fwh);
    fused_kernel<<<B_N * (T_LEN / C1), NT, 0, stream>>>(
        x, fw, fwh, fwh + WSBF_N, W_o, b_o, b_sk1, W_sk2, b_sk2, outp);
}

// Round 9
// 1582.093 us; speedup vs baseline: 1.2363x; 1.2330x over previous
//
#include <hip/hip_runtime.h>
#include <math.h>

#define T_LEN 65536
#define B_N   8
#define BT    (T_LEN * B_N)
#define L_N   16
#define RC    32
#define SC    64

#define C1    1024
#define HALO  1020
// BUFSZ ballast: total static LDS ~82.3 KB > 81920 B forces 1 block/CU so a
// second 16-wave block can never co-schedule (which would halve the register
// budget). Verified effective in R8 (LDS_Block_Size 82432).
#define BUFSZ 4800
#define NT    1024   // 16 waves: acc[4][4] = 64 VGPR/thread fits the 128 budget

// folded-weight per-layer arrays (14 x 32 = 448 floats)
#define A_AF0 0
#define A_AF1 32
#define A_AF2 64
#define A_CF0 96
#define A_CF1 128
#define A_BFC 160
#define A_AG0 192
#define A_AG1 224
#define A_AG2 256
#define A_CG0 288
#define A_CG1 320
#define A_BGC 352
#define A_BFF 384
#define A_BGF 416
#define FW_L  448
#define FW_BSUM (L_N * FW_L)      // 7168
#define FW_F32  (FW_BSUM + 64)    // 7232 floats
#define WSBF_N  (L_N * SC * RC)   // 32768 shorts
#define W1BF_N  (SC * SC)         // 4096 shorts

typedef float v2f __attribute__((ext_vector_type(2)));
typedef __attribute__((ext_vector_type(4))) float f4;
typedef __attribute__((ext_vector_type(4))) short bf4;
typedef __attribute__((ext_vector_type(8))) short bf8;

#define MFMA16(a, b, c) __builtin_amdgcn_mfma_f32_16x16x32_bf16(a, b, c, 0, 0, 0)

__device__ __forceinline__ v2f sp(float s) { return (v2f){s, s}; }
__device__ __forceinline__ float fast_rcp(float x) { return __builtin_amdgcn_rcpf(x); }

__device__ __forceinline__ float gated_fn(float fp, float gp) {
    float E = __expf(2.f * fp);
    float F = __expf(gp);
    return (E - 1.f) * F * fast_rcp((E + 1.f) * (F + 1.f));
}

__device__ __forceinline__ unsigned short f2bf(float f) {
    unsigned u = __float_as_uint(f);
    u += 0x7fffu + ((u >> 16) & 1u);
    return (unsigned short)(u >> 16);
}

// ---------------------------------------------------------------------------
// prep: fold gate weights (incl. mask-free biases BFF/BGF); Bsum; bf16 tables.
// ---------------------------------------------------------------------------
__global__ __launch_bounds__(256) void prep_kernel(
    const float* __restrict__ W_f, const float* __restrict__ W_g,
    const float* __restrict__ W_in, const float* __restrict__ b_in,
    const float* __restrict__ b_f, const float* __restrict__ b_g,
    const float* __restrict__ b_s, const float* __restrict__ W_s,
    const float* __restrict__ W_sk1, float* __restrict__ fw,
    short* __restrict__ fwh)
{
    int idx = blockIdx.x * 256 + threadIdx.x;
    if (idx < L_N * RC) {
        int i = idx >> 5, c = idx & 31;
        float af[3] = {0,0,0}, cf[3] = {0,0,0}, ag[3] = {0,0,0}, cg[3] = {0,0,0};
        for (int cin = 0; cin < RC; ++cin) {
            float wi = W_in[i * RC + cin];
            float bi = b_in[i * RC + cin];
            #pragma unroll
            for (int k = 0; k < 3; ++k) {
                float wf = W_f[((i * RC + c) * RC + cin) * 3 + k];
                float wg = W_g[((i * RC + c) * RC + cin) * 3 + k];
                af[k] = fmaf(wf, wi, af[k]);
                cf[k] = fmaf(wf, bi, cf[k]);
                ag[k] = fmaf(wg, wi, ag[k]);
                cg[k] = fmaf(wg, bi, cg[k]);
            }
        }
        float* p = fw + i * FW_L;
        float bfc = b_f[i * RC + c] + cf[2];
        float bgc = b_g[i * RC + c] + cg[2];
        p[A_AF0 + c] = af[0]; p[A_AF1 + c] = af[1]; p[A_AF2 + c] = af[2];
        p[A_CF0 + c] = cf[0]; p[A_CF1 + c] = cf[1];
        p[A_BFC + c] = bfc;
        p[A_AG0 + c] = ag[0]; p[A_AG1 + c] = ag[1]; p[A_AG2 + c] = ag[2];
        p[A_CG0 + c] = cg[0]; p[A_CG1 + c] = cg[1];
        p[A_BGC + c] = bgc;
        p[A_BFF + c] = bfc + cf[0] + cf[1];   // mask-free (t >= 2d) bias
        p[A_BGF + c] = bgc + cg[0] + cg[1];
    } else if (idx < L_N * RC + SC) {
        int s = idx - L_N * RC;
        float acc = 0.f;
        for (int i = 0; i < L_N; ++i) acc += b_s[i * SC + s];
        fw[FW_BSUM + s] = acc;
    } else if (idx < 576 + WSBF_N) {
        int j = idx - 576;
        fwh[j] = (short)f2bf(W_s[j]);            // [i][s][k] flat
    } else if (idx < 576 + WSBF_N + W1BF_N) {
        int j = idx - 576 - WSBF_N;
        fwh[WSBF_N + j] = (short)f2bf(W_sk1[j]); // [o][s] flat
    }
}

// ---------------------------------------------------------------------------
// fused kernel: residual chain (halo recompute) + per-layer bf16 skip-MFMA
// + head. One block of 16 waves per (b, 1024-t chunk); each thread covers
// 2 halo positions; each wave owns 4 t-tiles x 4 s-tiles (acc = 64 VGPR).
// ---------------------------------------------------------------------------
__global__ __launch_bounds__(NT)
void fused_kernel(
    const float* __restrict__ x, const float* __restrict__ fw,
    const short* __restrict__ Wsbf, const short* __restrict__ W1bf,
    const float* __restrict__ W_o, const float* __restrict__ b_o,
    const float* __restrict__ b_sk1, const float* __restrict__ W_sk2,
    const float* __restrict__ b_sk2, float* __restrict__ out)
{
    __shared__ __align__(16) float buf[2][BUFSZ];   // ballast-sized, see BUFSZ
    __shared__ __align__(16) char  Gb[1024 * 40];
    __shared__ __align__(16) float sGW[FW_L];
    __shared__ __align__(16) float sWo[32];
    __shared__ float sBo[1];
    __shared__ __align__(16) float sMisc[258]; // bsum[0..64) b1[64..128) w2[128..256) b2[256..258)

    int tid   = threadIdx.x;
    int b     = blockIdx.x >> 6;
    int chunk = blockIdx.x & 63;
    int t0    = chunk * C1;
    bool safe = (chunk >= 2);           // all t >= 2*d_max in computed range

    int wv   = tid >> 6;                // 0..15
    int lane = tid & 63;
    int m    = lane & 15;
    int q    = lane >> 4;

    if (tid < 64) { sMisc[tid] = fw[FW_BSUM + tid]; sMisc[64 + tid] = b_sk1[tid]; }
    if (tid >= 64 && tid < 192) sMisc[64 + tid] = W_sk2[tid - 64];
    if (tid >= 192 && tid < 194) sMisc[64 + tid] = b_sk2[tid - 192];

    const float* xb = x + (size_t)b * T_LEN;
    for (int p = tid; p < C1 + HALO; p += NT) {
        int t = t0 - HALO + p;
        buf[0][p] = (t >= 0) ? xb[t] : 0.f;
    }

    f4 acc[4][4];
    #pragma unroll
    for (int tt = 0; tt < 4; ++tt)
        #pragma unroll
        for (int st = 0; st < 4; ++st) acc[tt][st] = (f4){0.f, 0.f, 0.f, 0.f};

    int cur = 0;
    int rem = HALO;
    for (int i = 0; i < L_N; ++i) {
        int d    = 1 << (i & 7);
        int remN = rem - 2 * d;
        int lo   = HALO - remN;
        int nxt  = cur ^ 1;

        if (tid < FW_L) sGW[tid] = fw[i * FW_L + tid];
        if (tid >= FW_L && tid < FW_L + 32) sWo[tid - FW_L] = W_o[i * 32 + (tid - FW_L)];
        if (tid == FW_L + 32) sBo[0] = b_o[i];

        bf8 bfrag[4];
        #pragma unroll
        for (int st = 0; st < 4; ++st)
            bfrag[st] = *(const bf8*)(Wsbf + i * (SC * RC) + (st * 16 + m) * RC + q * 8);

        __syncthreads();   // weights staged; prev G consumed; buf[cur] ready

        // ---- per-thread taps/masks (2 positions) ----
        int  pj[2], row[2];
        bool inr[2], pok[2], on[2];
        float s2v[2], s1v[2], s0v[2], mm0[2], mm1[2];
        #pragma unroll
        for (int j = 0; j < 2; ++j) {
            int p = lo + tid + j * NT;
            int t = t0 - HALO + p;
            pj[j]  = p;
            row[j] = p - HALO;
            inr[j] = (p < C1 + HALO);
            pok[j] = inr[j] && (p >= HALO);
            on[j]  = inr[j] && (t >= 0);
            if (inr[j]) {
                s2v[j] = buf[cur][p];
                s1v[j] = buf[cur][p - d];
                s0v[j] = buf[cur][p - 2 * d];
            } else { s2v[j] = s1v[j] = s0v[j] = 0.f; }
            mm1[j] = (t - d     >= 0) ? 1.f : 0.f;
            mm0[j] = (t - 2 * d >= 0) ? 1.f : 0.f;
        }
        v2f s0p = {s0v[0], s0v[1]};
        v2f s1p = {s1v[0], s1v[1]};
        v2f s2p = {s2v[0], s2v[1]};
        v2f m0p = {mm0[0], mm0[1]};
        v2f m1p = {mm1[0], mm1[1]};
        v2f accp = {0.f, 0.f};

        // ---- two 16-channel halves: gate -> G(bf16) -> MFMA ----
        #pragma unroll
        for (int h = 0; h < 2; ++h) {
            #pragma unroll
            for (int c4g = 0; c4g < 4; ++c4g) {
                int c0 = h * 16 + c4g * 4;
                v2f fpv[4], gpv[4];
                {   // f-preactivation (disjoint lifetime from g-weights)
                    f4 va0 = *(const f4*)(sGW + A_AF0 + c0);
                    f4 va1 = *(const f4*)(sGW + A_AF1 + c0);
                    f4 va2 = *(const f4*)(sGW + A_AF2 + c0);
                    f4 vb  = *(const f4*)(sGW + (safe ? A_BFF : A_BFC) + c0);
                    if (safe) {
                        #pragma unroll
                        for (int e = 0; e < 4; ++e)
                            fpv[e] = sp(vb[e]) + s0p * sp(va0[e]) + s1p * sp(va1[e]) + s2p * sp(va2[e]);
                    } else {
                        f4 vc0 = *(const f4*)(sGW + A_CF0 + c0);
                        f4 vc1 = *(const f4*)(sGW + A_CF1 + c0);
                        #pragma unroll
                        for (int e = 0; e < 4; ++e)
                            fpv[e] = sp(vb[e]) + m0p * sp(vc0[e]) + m1p * sp(vc1[e])
                                   + s0p * sp(va0[e]) + s1p * sp(va1[e]) + s2p * sp(va2[e]);
                    }
                }
                {   // g-preactivation
                    f4 va0 = *(const f4*)(sGW + A_AG0 + c0);
                    f4 va1 = *(const f4*)(sGW + A_AG1 + c0);
                    f4 va2 = *(const f4*)(sGW + A_AG2 + c0);
                    f4 vb  = *(const f4*)(sGW + (safe ? A_BGF : A_BGC) + c0);
                    if (safe) {
                        #pragma unroll
                        for (int e = 0; e < 4; ++e)
                            gpv[e] = sp(vb[e]) + s0p * sp(va0[e]) + s1p * sp(va1[e]) + s2p * sp(va2[e]);
                    } else {
                        f4 vc0 = *(const f4*)(sGW + A_CG0 + c0);
                        f4 vc1 = *(const f4*)(sGW + A_CG1 + c0);
                        #pragma unroll
                        for (int e = 0; e < 4; ++e)
                            gpv[e] = sp(vb[e]) + m0p * sp(vc0[e]) + m1p * sp(vc1[e])
                                   + s0p * sp(va0[e]) + s1p * sp(va1[e]) + s2p * sp(va2[e]);
                    }
                }
                f4 vwo = *(const f4*)(sWo + c0);
                v2f gg[4];
                #pragma unroll
                for (int e = 0; e < 4; ++e) {
                    gg[e].x = gated_fn(fpv[e].x, gpv[e].x);
                    gg[e].y = gated_fn(fpv[e].y, gpv[e].y);
                    accp = accp + gg[e] * sp(vwo[e]);
                }
                #pragma unroll
                for (int j = 0; j < 2; ++j) {
                    if (pok[j]) {
                        bf4 v;
                        v[0] = (short)f2bf(j ? gg[0].y : gg[0].x);
                        v[1] = (short)f2bf(j ? gg[1].y : gg[1].x);
                        v[2] = (short)f2bf(j ? gg[2].y : gg[2].x);
                        v[3] = (short)f2bf(j ? gg[3].y : gg[3].x);
                        *(bf4*)(Gb + row[j] * 40 + c4g * 8) = v;
                    }
                }
            }

            // residual writeback (after both halves' acc, before the last sync)
            if (h == 1 && i < 15) {
                #pragma unroll
                for (int j = 0; j < 2; ++j) {
                    if (inr[j]) {
                        float a = j ? accp.y : accp.x;
                        float outv = s2v[j] + sBo[0] + a;
                        if (!safe && !on[j]) outv = 0.f;
                        buf[nxt][pj[j]] = outv;
                    }
                }
            }
            __syncthreads();   // G half ready

            // MFMA: A-frag carries this half's 16 channels, zeros elsewhere
            #pragma unroll
            for (int tt = 0; tt < 4; ++tt) {
                int gr = (wv * 4 + tt) * 16 + m;
                bf8 av = {0, 0, 0, 0, 0, 0, 0, 0};
                if ((q >> 1) == h) {
                    const char* ap = Gb + gr * 40 + (q & 1) * 16;
                    bf4 a0 = *(const bf4*)ap;
                    bf4 a1 = *(const bf4*)(ap + 8);
                    av = __builtin_shufflevector(a0, a1, 0, 1, 2, 3, 4, 5, 6, 7);
                }
                #pragma unroll
                for (int st = 0; st < 4; ++st)
                    acc[tt][st] = MFMA16(av, bfrag[st], acc[tt][st]);
            }
            if (h == 0) __syncthreads();   // G consumed before half-2 stores
        }
        cur = nxt;
        rem = remN;
    }

    // ---- head: per-wave, per-t-tile: bf16 LDS round-trip + MFMA(K=64) ----
    __syncthreads();   // layer-15 MFMA done; G region reused as scratch
    bf8 w1f[4][2];
    #pragma unroll
    for (int ot = 0; ot < 4; ++ot)
        #pragma unroll
        for (int kc = 0; kc < 2; ++kc)
            w1f[ot][kc] = *(const bf8*)(W1bf + (ot * 16 + m) * SC + kc * 32 + q * 8);

    char* hs = Gb + wv * 2304;   // 16 rows x 144 B per wave (16x2304 = 36.8 KB)
    float b20 = sMisc[256], b21 = sMisc[257];
    #pragma unroll
    for (int tt = 0; tt < 4; ++tt) {
        #pragma unroll
        for (int st = 0; st < 4; ++st) {
            int s = st * 16 + m;
            float bs = sMisc[s];
            #pragma unroll
            for (int r = 0; r < 4; ++r)
                *(unsigned short*)(hs + (q * 4 + r) * 144 + s * 2) = f2bf(acc[tt][st][r] + bs);
        }
        f4 hacc[4];
        #pragma unroll
        for (int ot = 0; ot < 4; ++ot) hacc[ot] = (f4){0.f, 0.f, 0.f, 0.f};
        #pragma unroll
        for (int kc = 0; kc < 2; ++kc) {
            bf8 af = *(const bf8*)(hs + m * 144 + kc * 64 + q * 16);
            #pragma unroll
            for (int ot = 0; ot < 4; ++ot)
                hacc[ot] = MFMA16(af, w1f[ot][kc], hacc[ot]);
        }
        float p0[4] = {0.f, 0.f, 0.f, 0.f}, p1[4] = {0.f, 0.f, 0.f, 0.f};
        #pragma unroll
        for (int ot = 0; ot < 4; ++ot) {
            int o = ot * 16 + m;
            float w20 = sMisc[128 + o], w21 = sMisc[192 + o], b1v = sMisc[64 + o];
            #pragma unroll
            for (int r = 0; r < 4; ++r) {
                float hv = fmaxf(hacc[ot][r] + b1v, 0.f);
                p0[r] = fmaf(w20, hv, p0[r]);
                p1[r] = fmaf(w21, hv, p1[r]);
            }
        }
        #pragma unroll
        for (int msk = 1; msk <= 8; msk <<= 1)
            #pragma unroll
            for (int r = 0; r < 4; ++r) {
                p0[r] += __shfl_xor(p0[r], msk);
                p1[r] += __shfl_xor(p1[r], msk);
            }
        if (m == 0) {
            int t = t0 + (wv * 4 + tt) * 16 + q * 4;
            size_t gi = (size_t)b * T_LEN + t;
            f4 mv, sv;
            #pragma unroll
            for (int r = 0; r < 4; ++r) {
                mv[r] = p0[r] + b20;
                sv[r] = __expf(0.5f * (p1[r] + b21));
            }
            *(f4*)(out + gi)      = mv;
            *(f4*)(out + BT + gi) = sv;
        }
    }
}

// ---------------------------------------------------------------------------
extern "C" void kernel_launch(void* const* d_in, const int* in_sizes, int n_in,
                              void* d_out, int out_size, void* d_ws, size_t ws_size,
                              hipStream_t stream) {
    const float* x     = (const float*)d_in[0];
    const float* W_in  = (const float*)d_in[1];
    const float* b_in  = (const float*)d_in[2];
    const float* W_f   = (const float*)d_in[3];
    const float* b_f   = (const float*)d_in[4];
    const float* W_g   = (const float*)d_in[5];
    const float* b_g   = (const float*)d_in[6];
    const float* W_s   = (const float*)d_in[7];
    const float* b_s   = (const float*)d_in[8];
    const float* W_o   = (const float*)d_in[9];
    const float* b_o   = (const float*)d_in[10];
    const float* W_sk1 = (const float*)d_in[11];
    const float* b_sk1 = (const float*)d_in[12];
    const float* W_sk2 = (const float*)d_in[13];
    const float* b_sk2 = (const float*)d_in[14];
    float* outp = (float*)d_out;

    float* fw  = (float*)d_ws;              // FW_F32 floats
    short* fwh = (short*)(fw + FW_F32);     // bf16 tables (Wsbf, W1bf)

    int prep_items = 576 + WSBF_N + W1BF_N;
    prep_kernel<<<(prep_items + 255) / 256, 256, 0, stream>>>(
        W_f, W_g, W_in, b_in, b_f, b_g, b_s, W_s, W_sk1, fw, fwh);
    fused_kernel<<<B_N * (T_LEN / C1), NT, 0, stream>>>(
        x, fw, fwh, fwh + WSBF_N, W_o, b_o, b_sk1, W_sk2, b_sk2, outp);
}